// Round 5
// baseline (362.308 us; speedup 1.0000x reference)
//
#include <hip/hip_runtime.h>

// ---------- types / helpers ----------
typedef __attribute__((ext_vector_type(8))) short short8;   // 8 bf16 = 4 VGPRs
typedef __attribute__((ext_vector_type(4))) short bf16x4;   // 4 bf16 = 2 VGPRs
typedef __attribute__((ext_vector_type(4))) float floatx4;  // MFMA C/D
typedef __attribute__((ext_vector_type(4))) float f32x4;

__device__ __forceinline__ short f2bf(float f) {
    union { float f; unsigned u; } v;
    v.f = f;
    unsigned r = v.u + 0x7fffu + ((v.u >> 16) & 1u);  // RNE
    return (short)(r >> 16);
}
__device__ __forceinline__ short8 cvt8(f32x4 a, f32x4 b) {
    short8 r;
    r[0] = f2bf(a[0]); r[1] = f2bf(a[1]); r[2] = f2bf(a[2]); r[3] = f2bf(a[3]);
    r[4] = f2bf(b[0]); r[5] = f2bf(b[1]); r[6] = f2bf(b[2]); r[7] = f2bf(b[3]);
    return r;
}
// round-half-up f32->bf16 pack of 4 (bias cancels in softmax normalization)
__device__ __forceinline__ bf16x4 pack4(float a, float b, float c, float d) {
    union { float f; unsigned u; } x;
    unsigned ua, ub, uc, ud;
    x.f = a; ua = (x.u + 0x8000u) >> 16;
    x.f = b; ub = (x.u + 0x8000u) >> 16;
    x.f = c; uc = (x.u + 0x8000u) >> 16;
    x.f = d; ud = (x.u + 0x8000u) >> 16;
    union { bf16x4 s; unsigned u2[2]; } r;
    r.u2[0] = ua | (ub << 16);
    r.u2[1] = uc | (ud << 16);
    return r.s;
}

#define MFMA_BF16(a, b, c) __builtin_amdgcn_mfma_f32_16x16x32_bf16((a), (b), (c), 0, 0, 0)

__device__ __forceinline__ floatx4 mfma16(bf16x4 a, bf16x4 b, floatx4 c) {
#if __has_builtin(__builtin_amdgcn_mfma_f32_16x16x16bf16_1k)
    return __builtin_amdgcn_mfma_f32_16x16x16bf16_1k(a, b, c, 0, 0, 0);
#else
    floatx4 d;
    asm volatile("v_mfma_f32_16x16x16_bf16 %0, %1, %2, %3"
                 : "=&v"(d) : "v"(a), "v"(b), "v"(c));
    return d;
#endif
}

__device__ __forceinline__ float fast_exp2(float x) {
#if __has_builtin(__builtin_amdgcn_exp2f)
    return __builtin_amdgcn_exp2f(x);
#else
    return exp2f(x);
#endif
}

// scale(1/8) * log2(e): softmax in exp2 domain, folded into Q at proj time
#define QSCALE_LOG2E 0.18033688011112042f

// ---------- 0) fp32 -> bf16 bulk convert, both x and ctx in one launch ----------
__global__ __launch_bounds__(256) void cvt_f32_bf16(const float* __restrict__ x,
                                                    const float* __restrict__ ctx,
                                                    short* __restrict__ xb,
                                                    short* __restrict__ ctxb) {
    const size_t i = ((size_t)blockIdx.x * 256 + threadIdx.x) * 8;
    const size_t NT = (size_t)4096 * 1024;
    const float* src = (i < NT) ? x : ctx;
    short* dst = (i < NT) ? xb : ctxb;
    const size_t j = (i < NT) ? i : i - NT;
    f32x4 a = *(const f32x4*)(src + j);
    f32x4 b = *(const f32x4*)(src + j + 4);
    *(short8*)(dst + j) = cvt8(a, b);
}

// ---------- 1) all 4 weight transposes in one launch ----------
__global__ __launch_bounds__(256) void transpose_all(const float* __restrict__ Wq,
                                                     const float* __restrict__ Wk,
                                                     const float* __restrict__ Wv,
                                                     const float* __restrict__ Wo,
                                                     short* __restrict__ WqT,
                                                     short* __restrict__ WkT,
                                                     short* __restrict__ WvT,
                                                     short* __restrict__ WoT) {
    const int z = blockIdx.z;
    const float* src = (z == 0) ? Wq : (z == 1) ? Wk : (z == 2) ? Wv : Wo;
    short* dst = (z == 0) ? WqT : (z == 1) ? WkT : (z == 2) ? WvT : WoT;
    const int R = (z < 3) ? 1024 : 512;
    const int C = (z < 3) ? 512 : 1024;
    const int c0 = blockIdx.x * 32;
    const int r0 = blockIdx.y * 32;
    if (c0 >= C || r0 >= R) return;
    __shared__ float tile[32][33];
    const int tx = threadIdx.x;
    const int ty = threadIdx.y;
#pragma unroll
    for (int i = 0; i < 32; i += 8)
        tile[ty + i][tx] = src[(r0 + ty + i) * C + c0 + tx];
    __syncthreads();
#pragma unroll
    for (int i = 0; i < 32; i += 8)
        dst[(c0 + ty + i) * R + r0 + tx] = f2bf(tile[tx][ty + i]);
}

// ---------- 2) fused QKV projection GEMM (128x128 tile, 4 waves, 64x64/wave) ----------
__global__ __launch_bounds__(256) void gemm_qkv(const short* __restrict__ xb,
                                                const short* __restrict__ ctxb,
                                                const short* __restrict__ WqT,
                                                const short* __restrict__ WkT,
                                                const short* __restrict__ WvT,
                                                short* __restrict__ Qw,
                                                short* __restrict__ Kw,
                                                short* __restrict__ Vtw) {
    const int z = blockIdx.z;
    const short* A  = (z == 0) ? xb : ctxb;
    const short* WT = (z == 0) ? WqT : (z == 1) ? WkT : WvT;
    const int w = threadIdx.x >> 6;
    const int lane = threadIdx.x & 63;
    const int quad = lane >> 4, ln = lane & 15;
    const int wr = w >> 1, wc = w & 1;
    const int row0 = blockIdx.x * 128 + wr * 64;
    const int col0 = blockIdx.y * 128 + wc * 64;

    floatx4 acc[4][4] = {};
    const short* aPtr = A + (row0 + ln) * 1024 + quad * 8;
    const short* wPtr = WT + (col0 + ln) * 1024 + quad * 8;

    for (int kk = 0; kk < 1024; kk += 32) {
        short8 af[4], bf[4];
#pragma unroll
        for (int i = 0; i < 4; ++i) af[i] = *(const short8*)(aPtr + i * 16 * 1024 + kk);
#pragma unroll
        for (int t = 0; t < 4; ++t) bf[t] = *(const short8*)(wPtr + t * 16 * 1024 + kk);
#pragma unroll
        for (int i = 0; i < 4; ++i)
#pragma unroll
            for (int t = 0; t < 4; ++t)
                acc[i][t] = MFMA_BF16(af[i], bf[t], acc[i][t]);
    }

    const float oscale = (z == 0) ? QSCALE_LOG2E : 1.0f;
    short* dst = (z == 0) ? Qw : (z == 1) ? Kw : Vtw;
#pragma unroll
    for (int i = 0; i < 4; ++i)
#pragma unroll
        for (int t = 0; t < 4; ++t)
#pragma unroll
            for (int r = 0; r < 4; ++r) {
                const int R = row0 + i * 16 + quad * 4 + r;
                const int C = col0 + t * 16 + ln;
                const int b = R >> 11, n = R & 2047;
                const int h = C >> 6, d = C & 63;
                const short val = f2bf(acc[i][t][r] * oscale);
                if (z < 2)
                    dst[((b * 8 + h) * 2048 + n) * 64 + d] = val;
                else
                    dst[((b * 8 + h) * 64 + d) * 2048 + n] = val;
            }
}

// ---------- 3) flash attention: register-only P transform, no LDS, no barriers ----------
// S^T = MFMA(A=K, B=Q): D[row=quad*4+r -> key][col=ln -> qrow]  (C-layout)
// which IS the B-operand layout B[k=quad*4+i][n=ln] of 16x16x16 MFMA.
// PV: O^T[d][qrow] += MFMA16(A=V^T-frag, B=P^T-frag). l via per-lane sums + 2 shuffles at end.
__global__ __launch_bounds__(256, 2) void attn_kernel(const short* __restrict__ Q,
                                                      const short* __restrict__ K,
                                                      const short* __restrict__ Vt,
                                                      float* __restrict__ Opart,
                                                      float* __restrict__ lbuf,
                                                      int chunkLen) {
    const int w = threadIdx.x >> 6;
    const int lane = threadIdx.x & 63;
    const int quad = lane >> 4;
    const int ln = lane & 15;
    const int q0 = blockIdx.x * 64;
    const int bh = blockIdx.y;  // b*8+h
    const int c = blockIdx.z;

    const short* Qbh = Q + bh * 2048 * 64;
    const short* Kbh = K + bh * 2048 * 64;
    const short* Vbh = Vt + bh * 64 * 2048;

    // Q fragments: B-operand of x32 MFMA: B[k=quad*8+j][n=ln] = Q[q0+w*16+ln][d]
    short8 qf[2];
    {
        const int qrow = q0 + w * 16 + ln;
        qf[0] = *(const short8*)(Qbh + qrow * 64 + quad * 8);
        qf[1] = *(const short8*)(Qbh + qrow * 64 + 32 + quad * 8);
    }

    floatx4 ot[4] = {};   // O^T: d-tile dt, lane holds d=dt*16+quad*4+r, qrow=ln
    float lp = 0.f;       // per-lane partial row sum (keys of this quad)

    // K frags: A-operand of x32: A[m=ln -> key][k=quad*8+j -> d]; [t][ks] flattened
    auto loadK = [&](int j0, short8* kf) {
#pragma unroll
        for (int t = 0; t < 4; ++t)
#pragma unroll
            for (int ks = 0; ks < 2; ++ks)
                kf[t * 2 + ks] = *(const short8*)(Kbh + (j0 + t * 16 + ln) * 64 + ks * 32 + quad * 8);
    };

    auto computeTile = [&](const short8* kf, int j0) {
        // V^T frags first (independent; latency covered by S+exp2):
        // A-operand of x16: A[m=ln -> d][k=quad*4+i -> key]
        bf16x4 vf[16];
#pragma unroll
        for (int dt = 0; dt < 4; ++dt)
#pragma unroll
            for (int t = 0; t < 4; ++t)
                vf[dt * 4 + t] = *(const bf16x4*)(Vbh + (dt * 16 + ln) * 2048 + j0 + t * 16 + quad * 4);

        floatx4 s[4] = {};
#pragma unroll
        for (int ks = 0; ks < 2; ++ks)
#pragma unroll
            for (int t = 0; t < 4; ++t)
                s[t] = MFMA_BF16(kf[t * 2 + ks], qf[ks], s[t]);

        bf16x4 pf[4];
#pragma unroll
        for (int t = 0; t < 4; ++t) {
            float p0 = fast_exp2(s[t][0]);
            float p1 = fast_exp2(s[t][1]);
            float p2 = fast_exp2(s[t][2]);
            float p3 = fast_exp2(s[t][3]);
            lp += (p0 + p1) + (p2 + p3);
            pf[t] = pack4(p0, p1, p2, p3);
        }
#pragma unroll
        for (int t = 0; t < 4; ++t)
#pragma unroll
            for (int dt = 0; dt < 4; ++dt)
                ot[dt] = mfma16(vf[dt * 4 + t], pf[t], ot[dt]);
    };

    const int j0s = c * chunkLen;
    const int jEnd = j0s + chunkLen;

    short8 kc[8];
    loadK(j0s, kc);
    // chunkLen is a multiple of 128 -> ping-pong double buffer
    for (int j0 = j0s; j0 < jEnd; j0 += 128) {
        short8 kn[8];
        loadK(j0 + 64, kn);            // prefetch while computing kc
        computeTile(kc, j0);
        if (j0 + 128 < jEnd) loadK(j0 + 128, kc);  // prefetch while computing kn
        computeTile(kn, j0 + 64);
    }

    // reduce l across quads (keys are split across quads)
    lp += __shfl_xor(lp, 16);
    lp += __shfl_xor(lp, 32);

    // epilogue: store partial O^T -> Opart[n][d] rows (4 contiguous d per dt)
    const int n = q0 + w * 16 + ln;
    float* obase = Opart + (((size_t)(c * 16 + bh) * 2048 + n) * 64) + quad * 4;
#pragma unroll
    for (int dt = 0; dt < 4; ++dt)
        *(f32x4*)(obase + dt * 16) = ot[dt];
    if (quad == 0)
        lbuf[(size_t)(c * 16 + bh) * 2048 + n] = lp;
}

// ---------- 4) combine partials -> bf16 attn out [4096][512] ----------
__global__ __launch_bounds__(256) void combine_kernel(const float* __restrict__ Opart,
                                                      const float* __restrict__ lbuf,
                                                      short* __restrict__ Aw,
                                                      int nchunks) {
    const int d = threadIdx.x;                     // 0..63
    const int rid = blockIdx.x * 4 + threadIdx.y;  // 0..32767
    const int bh = rid >> 11, n = rid & 2047;

    float L = 0.f, O = 0.f;
    for (int c = 0; c < nchunks; ++c) {
        L += lbuf[(size_t)(c * 16 + bh) * 2048 + n];
        O += Opart[(((size_t)(c * 16 + bh) * 2048 + n) * 64) + d];
    }
    const int b = bh >> 3, h = bh & 7;
    Aw[((size_t)(b * 2048 + n) * 512) + h * 64 + d] = f2bf(O / L);
}

// ---------- 5) output GEMM + bias ----------
__global__ __launch_bounds__(256) void gemm_final(const short* __restrict__ A,
                                                  const short* __restrict__ WoT,  // [1024][512]
                                                  const float* __restrict__ bias, // [1024]
                                                  float* __restrict__ out) {
    const int w = threadIdx.x >> 6;
    const int lane = threadIdx.x & 63;
    const int quad = lane >> 4, ln = lane & 15;
    const int wr = w >> 1, wc = w & 1;
    const int row0 = blockIdx.x * 128 + wr * 64;
    const int col0 = blockIdx.y * 128 + wc * 64;

    floatx4 acc[4][4] = {};
    const short* aPtr = A + (row0 + ln) * 512 + quad * 8;
    const short* wPtr = WoT + (col0 + ln) * 512 + quad * 8;

    for (int kk = 0; kk < 512; kk += 32) {
        short8 af[4], bf[4];
#pragma unroll
        for (int i = 0; i < 4; ++i) af[i] = *(const short8*)(aPtr + i * 16 * 512 + kk);
#pragma unroll
        for (int t = 0; t < 4; ++t) bf[t] = *(const short8*)(wPtr + t * 16 * 512 + kk);
#pragma unroll
        for (int i = 0; i < 4; ++i)
#pragma unroll
            for (int t = 0; t < 4; ++t)
                acc[i][t] = MFMA_BF16(af[i], bf[t], acc[i][t]);
    }
#pragma unroll
    for (int i = 0; i < 4; ++i)
#pragma unroll
        for (int t = 0; t < 4; ++t)
#pragma unroll
            for (int r = 0; r < 4; ++r) {
                const int R = row0 + i * 16 + quad * 4 + r;
                const int C = col0 + t * 16 + ln;
                out[(size_t)R * 1024 + C] = acc[i][t][r] + bias[C];
            }
}

// ---------- launcher ----------
extern "C" void kernel_launch(void* const* d_in, const int* in_sizes, int n_in,
                              void* d_out, int out_size, void* d_ws, size_t ws_size,
                              hipStream_t stream) {
    const float* x   = (const float*)d_in[0];  // [2,2048,1024] f32
    const float* ctx = (const float*)d_in[1];
    const float* Wq  = (const float*)d_in[2];  // [1024,512]
    const float* Wk  = (const float*)d_in[3];
    const float* Wv  = (const float*)d_in[4];
    const float* Wo  = (const float*)d_in[5];  // [512,1024]
    const float* bo  = (const float*)d_in[6];  // [1024]
    float* out = (float*)d_out;                // [2,2048,1024] f32

    char* ws = (char*)d_ws;
    size_t off = 0;
    auto alloc = [&](size_t bytes) { char* p = ws + off; off += (bytes + 255) & ~(size_t)255; return p; };

    short* WqT  = (short*)alloc(512 * 1024 * 2);
    short* WkT  = (short*)alloc(512 * 1024 * 2);
    short* WvT  = (short*)alloc(512 * 1024 * 2);
    short* WoT  = (short*)alloc(1024 * 512 * 2);
    short* xb   = (short*)alloc((size_t)4096 * 1024 * 2);
    short* ctxb = (short*)alloc((size_t)4096 * 1024 * 2);
    short* Qw   = (short*)alloc((size_t)16 * 2048 * 64 * 2);
    short* Kw   = (short*)alloc((size_t)16 * 2048 * 64 * 2);
    short* Vtw  = (short*)alloc((size_t)16 * 2048 * 64 * 2);
    short* Aw   = (short*)alloc((size_t)4096 * 512 * 2);
    size_t base = off;
    const size_t perchunk = (size_t)16 * 2048 * 64 * 4 + (size_t)16 * 2048 * 4 + 512;
    int nchunks = 4;
    while (nchunks > 1 && base + (size_t)nchunks * perchunk > ws_size) nchunks >>= 1;
    float* Opart = (float*)alloc((size_t)nchunks * 16 * 2048 * 64 * 4);
    float* lbuf  = (float*)alloc((size_t)nchunks * 16 * 2048 * 4);
    const int chunkLen = 2048 / nchunks;

    cvt_f32_bf16<<<4096, 256, 0, stream>>>(x, ctx, xb, ctxb);
    transpose_all<<<dim3(32, 32, 4), dim3(32, 8), 0, stream>>>(Wq, Wk, Wv, Wo, WqT, WkT, WvT, WoT);

    gemm_qkv<<<dim3(32, 4, 3), 256, 0, stream>>>(xb, ctxb, WqT, WkT, WvT, Qw, Kw, Vtw);

    attn_kernel<<<dim3(32, 16, nchunks), 256, 0, stream>>>(Qw, Kw, Vtw, Opart, lbuf, chunkLen);
    combine_kernel<<<dim3(8192), dim3(64, 4), 0, stream>>>(Opart, lbuf, Aw, nchunks);

    gemm_final<<<dim3(32, 8), 256, 0, stream>>>(Aw, WoT, bo, out);
}

// Round 6
// 225.795 us; speedup vs baseline: 1.6046x; 1.6046x over previous
//
#include <hip/hip_runtime.h>

// ---------- types / helpers ----------
typedef __attribute__((ext_vector_type(8))) short short8;   // 8 bf16 = 4 VGPRs
typedef __attribute__((ext_vector_type(4))) short bf16x4;   // 4 bf16 = 2 VGPRs
typedef __attribute__((ext_vector_type(4))) float floatx4;  // MFMA C/D
typedef __attribute__((ext_vector_type(4))) float f32x4;

__device__ __forceinline__ short f2bf(float f) {
    union { float f; unsigned u; } v;
    v.f = f;
    unsigned r = v.u + 0x7fffu + ((v.u >> 16) & 1u);  // RNE
    return (short)(r >> 16);
}
__device__ __forceinline__ short8 cvt8(f32x4 a, f32x4 b) {
    short8 r;
    r[0] = f2bf(a[0]); r[1] = f2bf(a[1]); r[2] = f2bf(a[2]); r[3] = f2bf(a[3]);
    r[4] = f2bf(b[0]); r[5] = f2bf(b[1]); r[6] = f2bf(b[2]); r[7] = f2bf(b[3]);
    return r;
}
// round-half-up f32->bf16 pack of 4 (bias cancels in softmax normalization)
__device__ __forceinline__ bf16x4 pack4(float a, float b, float c, float d) {
    union { float f; unsigned u; } x;
    unsigned ua, ub, uc, ud;
    x.f = a; ua = (x.u + 0x8000u) >> 16;
    x.f = b; ub = (x.u + 0x8000u) >> 16;
    x.f = c; uc = (x.u + 0x8000u) >> 16;
    x.f = d; ud = (x.u + 0x8000u) >> 16;
    union { bf16x4 s; unsigned u2[2]; } r;
    r.u2[0] = ua | (ub << 16);
    r.u2[1] = uc | (ud << 16);
    return r.s;
}

#define MFMA_BF16(a, b, c) __builtin_amdgcn_mfma_f32_16x16x32_bf16((a), (b), (c), 0, 0, 0)

__device__ __forceinline__ floatx4 mfma16(bf16x4 a, bf16x4 b, floatx4 c) {
#if __has_builtin(__builtin_amdgcn_mfma_f32_16x16x16bf16_1k)
    return __builtin_amdgcn_mfma_f32_16x16x16bf16_1k(a, b, c, 0, 0, 0);
#else
    floatx4 d;
    asm volatile("v_mfma_f32_16x16x16_bf16 %0, %1, %2, %3"
                 : "=&v"(d) : "v"(a), "v"(b), "v"(c));
    return d;
#endif
}

__device__ __forceinline__ float fast_exp2(float x) {
#if __has_builtin(__builtin_amdgcn_exp2f)
    return __builtin_amdgcn_exp2f(x);
#else
    return exp2f(x);
#endif
}

// scale(1/8) * log2(e): softmax in exp2 domain, folded into Q at proj time
#define QSCALE_LOG2E 0.18033688011112042f

// ---------- 0) fp32 -> bf16 bulk convert, both x and ctx in one launch ----------
__global__ __launch_bounds__(256) void cvt_f32_bf16(const float* __restrict__ x,
                                                    const float* __restrict__ ctx,
                                                    short* __restrict__ xb,
                                                    short* __restrict__ ctxb) {
    const size_t i = ((size_t)blockIdx.x * 256 + threadIdx.x) * 8;
    const size_t NT = (size_t)4096 * 1024;
    const float* src = (i < NT) ? x : ctx;
    short* dst = (i < NT) ? xb : ctxb;
    const size_t j = (i < NT) ? i : i - NT;
    f32x4 a = *(const f32x4*)(src + j);
    f32x4 b = *(const f32x4*)(src + j + 4);
    *(short8*)(dst + j) = cvt8(a, b);
}

// ---------- 1) all 4 weight transposes in one launch ----------
__global__ __launch_bounds__(256) void transpose_all(const float* __restrict__ Wq,
                                                     const float* __restrict__ Wk,
                                                     const float* __restrict__ Wv,
                                                     const float* __restrict__ Wo,
                                                     short* __restrict__ WqT,
                                                     short* __restrict__ WkT,
                                                     short* __restrict__ WvT,
                                                     short* __restrict__ WoT) {
    const int z = blockIdx.z;
    const float* src = (z == 0) ? Wq : (z == 1) ? Wk : (z == 2) ? Wv : Wo;
    short* dst = (z == 0) ? WqT : (z == 1) ? WkT : (z == 2) ? WvT : WoT;
    const int R = (z < 3) ? 1024 : 512;
    const int C = (z < 3) ? 512 : 1024;
    const int c0 = blockIdx.x * 32;
    const int r0 = blockIdx.y * 32;
    if (c0 >= C || r0 >= R) return;
    __shared__ float tile[32][33];
    const int tx = threadIdx.x;
    const int ty = threadIdx.y;
#pragma unroll
    for (int i = 0; i < 32; i += 8)
        tile[ty + i][tx] = src[(r0 + ty + i) * C + c0 + tx];
    __syncthreads();
#pragma unroll
    for (int i = 0; i < 32; i += 8)
        dst[(c0 + ty + i) * R + r0 + tx] = f2bf(tile[tx][ty + i]);
}

// ---------- 2) fused QKV projection GEMM (128x128 tile, 4 waves, 64x64/wave) ----------
__global__ __launch_bounds__(256) void gemm_qkv(const short* __restrict__ xb,
                                                const short* __restrict__ ctxb,
                                                const short* __restrict__ WqT,
                                                const short* __restrict__ WkT,
                                                const short* __restrict__ WvT,
                                                short* __restrict__ Qw,
                                                short* __restrict__ Kw,
                                                short* __restrict__ Vtw) {
    const int z = blockIdx.z;
    const short* A  = (z == 0) ? xb : ctxb;
    const short* WT = (z == 0) ? WqT : (z == 1) ? WkT : WvT;
    const int w = threadIdx.x >> 6;
    const int lane = threadIdx.x & 63;
    const int quad = lane >> 4, ln = lane & 15;
    const int wr = w >> 1, wc = w & 1;
    const int row0 = blockIdx.x * 128 + wr * 64;
    const int col0 = blockIdx.y * 128 + wc * 64;

    floatx4 acc[4][4] = {};
    const short* aPtr = A + (row0 + ln) * 1024 + quad * 8;
    const short* wPtr = WT + (col0 + ln) * 1024 + quad * 8;

    for (int kk = 0; kk < 1024; kk += 32) {
        short8 af[4], bf[4];
#pragma unroll
        for (int i = 0; i < 4; ++i) af[i] = *(const short8*)(aPtr + i * 16 * 1024 + kk);
#pragma unroll
        for (int t = 0; t < 4; ++t) bf[t] = *(const short8*)(wPtr + t * 16 * 1024 + kk);
#pragma unroll
        for (int i = 0; i < 4; ++i)
#pragma unroll
            for (int t = 0; t < 4; ++t)
                acc[i][t] = MFMA_BF16(af[i], bf[t], acc[i][t]);
    }

    const float oscale = (z == 0) ? QSCALE_LOG2E : 1.0f;
    short* dst = (z == 0) ? Qw : (z == 1) ? Kw : Vtw;
#pragma unroll
    for (int i = 0; i < 4; ++i)
#pragma unroll
        for (int t = 0; t < 4; ++t)
#pragma unroll
            for (int r = 0; r < 4; ++r) {
                const int R = row0 + i * 16 + quad * 4 + r;
                const int C = col0 + t * 16 + ln;
                const int b = R >> 11, n = R & 2047;
                const int h = C >> 6, d = C & 63;
                const short val = f2bf(acc[i][t][r] * oscale);
                if (z < 2)
                    dst[((b * 8 + h) * 2048 + n) * 64 + d] = val;
                else
                    dst[((b * 8 + h) * 64 + d) * 2048 + n] = val;
            }
}

// ---------- 3) flash attention: cooperative double-buffered LDS staging of K/V,
//              register-only P transform (S^T trick), no shuffles in loop ----------
// S^T = MFMA(A=K, B=Q): C-layout D[key=quad*4+r][qrow=ln] == B-operand layout of
// 16x16x16 MFMA, so P^T converts to PV input purely in registers.
// K tile [64 keys][64 d] and V^T tile [64 d][64 keys] staged in LDS, shared by
// all 4 waves (4x traffic cut), padded stride 72 (144B, 16B-aligned rows).
__global__ __launch_bounds__(256, 3) void attn_kernel(const short* __restrict__ Q,
                                                      const short* __restrict__ K,
                                                      const short* __restrict__ Vt,
                                                      float* __restrict__ Opart,
                                                      float* __restrict__ lbuf,
                                                      int chunkLen) {
    const int tid = threadIdx.x;
    const int w = tid >> 6;
    const int lane = tid & 63;
    const int quad = lane >> 4;
    const int ln = lane & 15;
    const int q0 = blockIdx.x * 64;
    const int bh = blockIdx.y;  // b*8+h
    const int c = blockIdx.z;

    __shared__ __align__(16) short klds[2][64][72];
    __shared__ __align__(16) short vlds[2][64][72];

    const short* Qbh = Q + bh * 2048 * 64;
    const short* Kbh = K + bh * 2048 * 64;
    const short* Vbh = Vt + bh * 64 * 2048;

    // Q fragments: B-operand of x32 MFMA: B[k=quad*8+j][n=ln] = Q[q0+w*16+ln][d]
    short8 qf[2];
    {
        const int qrow = q0 + w * 16 + ln;
        qf[0] = *(const short8*)(Qbh + qrow * 64 + quad * 8);
        qf[1] = *(const short8*)(Qbh + qrow * 64 + 32 + quad * 8);
    }

    floatx4 ot[4] = {};   // O^T: lane holds d=dt*16+quad*4+r, qrow=ln
    float lp = 0.f;       // per-lane partial row sum

    const int sr = tid >> 3;          // staging row 0..31
    const int sc = (tid & 7) * 8;     // staging col (shorts)

    auto computeTile = [&](int b) {
        // K frags: A-op of x32: A[m=ln -> key][k=quad*8+j -> d]
        short8 kf[8];
#pragma unroll
        for (int t = 0; t < 4; ++t)
#pragma unroll
            for (int ks = 0; ks < 2; ++ks)
                kf[t * 2 + ks] = *(const short8*)(&klds[b][t * 16 + ln][ks * 32 + quad * 8]);
        // V^T frags: A-op of x16: A[m=ln -> d][k=quad*4+i -> key]
        bf16x4 vf[16];
#pragma unroll
        for (int dt = 0; dt < 4; ++dt)
#pragma unroll
            for (int t = 0; t < 4; ++t)
                vf[dt * 4 + t] = *(const bf16x4*)(&vlds[b][dt * 16 + ln][t * 16 + quad * 4]);

        floatx4 s[4] = {};
#pragma unroll
        for (int ks = 0; ks < 2; ++ks)
#pragma unroll
            for (int t = 0; t < 4; ++t)
                s[t] = MFMA_BF16(kf[t * 2 + ks], qf[ks], s[t]);

        bf16x4 pf[4];
#pragma unroll
        for (int t = 0; t < 4; ++t) {
            float p0 = fast_exp2(s[t][0]);
            float p1 = fast_exp2(s[t][1]);
            float p2 = fast_exp2(s[t][2]);
            float p3 = fast_exp2(s[t][3]);
            lp += (p0 + p1) + (p2 + p3);
            pf[t] = pack4(p0, p1, p2, p3);
        }
#pragma unroll
        for (int t = 0; t < 4; ++t)
#pragma unroll
            for (int dt = 0; dt < 4; ++dt)
                ot[dt] = mfma16(vf[dt * 4 + t], pf[t], ot[dt]);
    };

    const int j0s = c * chunkLen;
    const int nt = chunkLen >> 6;

    {   // prologue: stage tile 0 into buffer 0
        short8 k0 = *(const short8*)(Kbh + j0s * 64 + tid * 8);
        short8 k1 = *(const short8*)(Kbh + j0s * 64 + (tid + 256) * 8);
        short8 v0 = *(const short8*)(Vbh + sr * 2048 + j0s + sc);
        short8 v1 = *(const short8*)(Vbh + (sr + 32) * 2048 + j0s + sc);
        *(short8*)(&klds[0][sr][sc]) = k0;
        *(short8*)(&klds[0][sr + 32][sc]) = k1;
        *(short8*)(&vlds[0][sr][sc]) = v0;
        *(short8*)(&vlds[0][sr + 32][sc]) = v1;
    }
    __syncthreads();

    for (int it = 0; it < nt; ++it) {
        short8 k0, k1, v0, v1;
        const bool more = (it + 1 < nt);
        if (more) {  // issue next-tile global loads before compute (latency overlap)
            const int jn = j0s + (it + 1) * 64;
            k0 = *(const short8*)(Kbh + jn * 64 + tid * 8);
            k1 = *(const short8*)(Kbh + jn * 64 + (tid + 256) * 8);
            v0 = *(const short8*)(Vbh + sr * 2048 + jn + sc);
            v1 = *(const short8*)(Vbh + (sr + 32) * 2048 + jn + sc);
        }
        computeTile(it & 1);
        if (more) {
            const int nb = (it + 1) & 1;
            *(short8*)(&klds[nb][sr][sc]) = k0;
            *(short8*)(&klds[nb][sr + 32][sc]) = k1;
            *(short8*)(&vlds[nb][sr][sc]) = v0;
            *(short8*)(&vlds[nb][sr + 32][sc]) = v1;
        }
        __syncthreads();
    }

    // reduce l across quads (keys are split across quads)
    lp += __shfl_xor(lp, 16);
    lp += __shfl_xor(lp, 32);

    // epilogue: store partial O^T -> Opart[n][d] rows (4 contiguous d per dt)
    const int n = q0 + w * 16 + ln;
    float* obase = Opart + (((size_t)(c * 16 + bh) * 2048 + n) * 64) + quad * 4;
#pragma unroll
    for (int dt = 0; dt < 4; ++dt)
        *(f32x4*)(obase + dt * 16) = ot[dt];
    if (quad == 0)
        lbuf[(size_t)(c * 16 + bh) * 2048 + n] = lp;
}

// ---------- 4) combine partials -> bf16 attn out [4096][512] ----------
__global__ __launch_bounds__(256) void combine_kernel(const float* __restrict__ Opart,
                                                      const float* __restrict__ lbuf,
                                                      short* __restrict__ Aw,
                                                      int nchunks) {
    const int d = threadIdx.x;                     // 0..63
    const int rid = blockIdx.x * 4 + threadIdx.y;  // 0..32767
    const int bh = rid >> 11, n = rid & 2047;

    float L = 0.f, O = 0.f;
    for (int c = 0; c < nchunks; ++c) {
        L += lbuf[(size_t)(c * 16 + bh) * 2048 + n];
        O += Opart[(((size_t)(c * 16 + bh) * 2048 + n) * 64) + d];
    }
    const int b = bh >> 3, h = bh & 7;
    Aw[((size_t)(b * 2048 + n) * 512) + h * 64 + d] = f2bf(O / L);
}

// ---------- 5) output GEMM + bias ----------
__global__ __launch_bounds__(256) void gemm_final(const short* __restrict__ A,
                                                  const short* __restrict__ WoT,  // [1024][512]
                                                  const float* __restrict__ bias, // [1024]
                                                  float* __restrict__ out) {
    const int w = threadIdx.x >> 6;
    const int lane = threadIdx.x & 63;
    const int quad = lane >> 4, ln = lane & 15;
    const int wr = w >> 1, wc = w & 1;
    const int row0 = blockIdx.x * 128 + wr * 64;
    const int col0 = blockIdx.y * 128 + wc * 64;

    floatx4 acc[4][4] = {};
    const short* aPtr = A + (row0 + ln) * 512 + quad * 8;
    const short* wPtr = WoT + (col0 + ln) * 512 + quad * 8;

    for (int kk = 0; kk < 512; kk += 32) {
        short8 af[4], bf[4];
#pragma unroll
        for (int i = 0; i < 4; ++i) af[i] = *(const short8*)(aPtr + i * 16 * 512 + kk);
#pragma unroll
        for (int t = 0; t < 4; ++t) bf[t] = *(const short8*)(wPtr + t * 16 * 512 + kk);
#pragma unroll
        for (int i = 0; i < 4; ++i)
#pragma unroll
            for (int t = 0; t < 4; ++t)
                acc[i][t] = MFMA_BF16(af[i], bf[t], acc[i][t]);
    }
#pragma unroll
    for (int i = 0; i < 4; ++i)
#pragma unroll
        for (int t = 0; t < 4; ++t)
#pragma unroll
            for (int r = 0; r < 4; ++r) {
                const int R = row0 + i * 16 + quad * 4 + r;
                const int C = col0 + t * 16 + ln;
                out[(size_t)R * 1024 + C] = acc[i][t][r] + bias[C];
            }
}

// ---------- launcher ----------
extern "C" void kernel_launch(void* const* d_in, const int* in_sizes, int n_in,
                              void* d_out, int out_size, void* d_ws, size_t ws_size,
                              hipStream_t stream) {
    const float* x   = (const float*)d_in[0];  // [2,2048,1024] f32
    const float* ctx = (const float*)d_in[1];
    const float* Wq  = (const float*)d_in[2];  // [1024,512]
    const float* Wk  = (const float*)d_in[3];
    const float* Wv  = (const float*)d_in[4];
    const float* Wo  = (const float*)d_in[5];  // [512,1024]
    const float* bo  = (const float*)d_in[6];  // [1024]
    float* out = (float*)d_out;                // [2,2048,1024] f32

    char* ws = (char*)d_ws;
    size_t off = 0;
    auto alloc = [&](size_t bytes) { char* p = ws + off; off += (bytes + 255) & ~(size_t)255; return p; };

    short* WqT  = (short*)alloc(512 * 1024 * 2);
    short* WkT  = (short*)alloc(512 * 1024 * 2);
    short* WvT  = (short*)alloc(512 * 1024 * 2);
    short* WoT  = (short*)alloc(1024 * 512 * 2);
    short* xb   = (short*)alloc((size_t)4096 * 1024 * 2);
    short* ctxb = (short*)alloc((size_t)4096 * 1024 * 2);
    short* Qw   = (short*)alloc((size_t)16 * 2048 * 64 * 2);
    short* Kw   = (short*)alloc((size_t)16 * 2048 * 64 * 2);
    short* Vtw  = (short*)alloc((size_t)16 * 2048 * 64 * 2);
    short* Aw   = (short*)alloc((size_t)4096 * 512 * 2);
    size_t base = off;
    const size_t perchunk = (size_t)16 * 2048 * 64 * 4 + (size_t)16 * 2048 * 4 + 512;
    int nchunks = 4;
    while (nchunks > 1 && base + (size_t)nchunks * perchunk > ws_size) nchunks >>= 1;
    float* Opart = (float*)alloc((size_t)nchunks * 16 * 2048 * 64 * 4);
    float* lbuf  = (float*)alloc((size_t)nchunks * 16 * 2048 * 4);
    const int chunkLen = 2048 / nchunks;

    cvt_f32_bf16<<<4096, 256, 0, stream>>>(x, ctx, xb, ctxb);
    transpose_all<<<dim3(32, 32, 4), dim3(32, 8), 0, stream>>>(Wq, Wk, Wv, Wo, WqT, WkT, WvT, WoT);

    gemm_qkv<<<dim3(32, 4, 3), 256, 0, stream>>>(xb, ctxb, WqT, WkT, WvT, Qw, Kw, Vtw);

    attn_kernel<<<dim3(32, 16, nchunks), 256, 0, stream>>>(Qw, Kw, Vtw, Opart, lbuf, chunkLen);
    combine_kernel<<<dim3(8192), dim3(64, 4), 0, stream>>>(Opart, lbuf, Aw, nchunks);

    gemm_final<<<dim3(32, 8), 256, 0, stream>>>(Aw, WoT, bo, out);
}

// Round 7
// 178.037 us; speedup vs baseline: 2.0350x; 1.2682x over previous
//
#include <hip/hip_runtime.h>

// ---------- types / helpers ----------
typedef __attribute__((ext_vector_type(8))) short short8;   // 8 bf16 = 4 VGPRs
typedef __attribute__((ext_vector_type(4))) short bf16x4;   // 4 bf16 = 2 VGPRs
typedef __attribute__((ext_vector_type(4))) float floatx4;  // MFMA C/D
typedef __attribute__((ext_vector_type(4))) float f32x4;

__device__ __forceinline__ short f2bf(float f) {
    union { float f; unsigned u; } v;
    v.f = f;
    unsigned r = v.u + 0x7fffu + ((v.u >> 16) & 1u);  // RNE
    return (short)(r >> 16);
}
__device__ __forceinline__ short8 cvt8(f32x4 a, f32x4 b) {
    short8 r;
    r[0] = f2bf(a[0]); r[1] = f2bf(a[1]); r[2] = f2bf(a[2]); r[3] = f2bf(a[3]);
    r[4] = f2bf(b[0]); r[5] = f2bf(b[1]); r[6] = f2bf(b[2]); r[7] = f2bf(b[3]);
    return r;
}
// round-half-up f32->bf16 pack of 4 (bias cancels in softmax normalization)
__device__ __forceinline__ bf16x4 pack4(float a, float b, float c, float d) {
    union { float f; unsigned u; } x;
    unsigned ua, ub, uc, ud;
    x.f = a; ua = (x.u + 0x8000u) >> 16;
    x.f = b; ub = (x.u + 0x8000u) >> 16;
    x.f = c; uc = (x.u + 0x8000u) >> 16;
    x.f = d; ud = (x.u + 0x8000u) >> 16;
    union { bf16x4 s; unsigned u2[2]; } r;
    r.u2[0] = ua | (ub << 16);
    r.u2[1] = uc | (ud << 16);
    return r.s;
}

#define MFMA_BF16(a, b, c) __builtin_amdgcn_mfma_f32_16x16x32_bf16((a), (b), (c), 0, 0, 0)

__device__ __forceinline__ floatx4 mfma16(bf16x4 a, bf16x4 b, floatx4 c) {
#if __has_builtin(__builtin_amdgcn_mfma_f32_16x16x16bf16_1k)
    return __builtin_amdgcn_mfma_f32_16x16x16bf16_1k(a, b, c, 0, 0, 0);
#else
    floatx4 d;
    asm volatile("v_mfma_f32_16x16x16_bf16 %0, %1, %2, %3"
                 : "=&v"(d) : "v"(a), "v"(b), "v"(c));
    return d;
#endif
}

__device__ __forceinline__ float fast_exp2(float x) {
#if __has_builtin(__builtin_amdgcn_exp2f)
    return __builtin_amdgcn_exp2f(x);
#else
    return exp2f(x);
#endif
}

// scale(1/8) * log2(e): softmax in exp2 domain, folded into Q at proj time
#define QSCALE_LOG2E 0.18033688011112042f

// ---------- 0) fp32 -> bf16 bulk convert, both x and ctx in one launch ----------
__global__ __launch_bounds__(256) void cvt_f32_bf16(const float* __restrict__ x,
                                                    const float* __restrict__ ctx,
                                                    short* __restrict__ xb,
                                                    short* __restrict__ ctxb) {
    const size_t i = ((size_t)blockIdx.x * 256 + threadIdx.x) * 8;
    const size_t NT = (size_t)4096 * 1024;
    const float* src = (i < NT) ? x : ctx;
    short* dst = (i < NT) ? xb : ctxb;
    const size_t j = (i < NT) ? i : i - NT;
    f32x4 a = *(const f32x4*)(src + j);
    f32x4 b = *(const f32x4*)(src + j + 4);
    *(short8*)(dst + j) = cvt8(a, b);
}

// ---------- 1) all 4 weight transposes in one launch ----------
__global__ __launch_bounds__(256) void transpose_all(const float* __restrict__ Wq,
                                                     const float* __restrict__ Wk,
                                                     const float* __restrict__ Wv,
                                                     const float* __restrict__ Wo,
                                                     short* __restrict__ WqT,
                                                     short* __restrict__ WkT,
                                                     short* __restrict__ WvT,
                                                     short* __restrict__ WoT) {
    const int z = blockIdx.z;
    const float* src = (z == 0) ? Wq : (z == 1) ? Wk : (z == 2) ? Wv : Wo;
    short* dst = (z == 0) ? WqT : (z == 1) ? WkT : (z == 2) ? WvT : WoT;
    const int R = (z < 3) ? 1024 : 512;
    const int C = (z < 3) ? 512 : 1024;
    const int c0 = blockIdx.x * 32;
    const int r0 = blockIdx.y * 32;
    if (c0 >= C || r0 >= R) return;
    __shared__ float tile[32][33];
    const int tx = threadIdx.x;
    const int ty = threadIdx.y;
#pragma unroll
    for (int i = 0; i < 32; i += 8)
        tile[ty + i][tx] = src[(r0 + ty + i) * C + c0 + tx];
    __syncthreads();
#pragma unroll
    for (int i = 0; i < 32; i += 8)
        dst[(c0 + ty + i) * R + r0 + tx] = f2bf(tile[tx][ty + i]);
}

// ---------- 2) fused QKV projection GEMM, LDS-staged double-buffer ----------
// C[4096][512] = A[4096][1024] @ W; WT is [512][1024] (N-major over K).
// Block 256 thr (4 waves), tile BM=64 x BN=128, BK=32; wave tile 32x64.
// z=0: Q (scaled), [bh][n][64]; z=1: K, [bh][n][64]; z=2: V^T, [bh][64][n].
__global__ __launch_bounds__(256, 4) void gemm_qkv(const short* __restrict__ xb,
                                                   const short* __restrict__ ctxb,
                                                   const short* __restrict__ WqT,
                                                   const short* __restrict__ WkT,
                                                   const short* __restrict__ WvT,
                                                   short* __restrict__ Qw,
                                                   short* __restrict__ Kw,
                                                   short* __restrict__ Vtw) {
    const int z = blockIdx.z;
    const short* A  = (z == 0) ? xb : ctxb;
    const short* WT = (z == 0) ? WqT : (z == 1) ? WkT : WvT;
    const int tid = threadIdx.x;
    const int w = tid >> 6;
    const int lane = tid & 63;
    const int quad = lane >> 4, ln = lane & 15;
    const int wr = w >> 1, wc = w & 1;
    const int row0 = blockIdx.x * 64;
    const int col0 = blockIdx.y * 128;

    __shared__ __align__(16) short Alds[2][64][32];
    __shared__ __align__(16) short Blds[2][128][32];

    const int srow = tid >> 2;          // 0..63
    const int scol = (tid & 3) * 8;     // 0,8,16,24
    const short* aG = A + (size_t)(row0 + srow) * 1024 + scol;
    const short* bG0 = WT + (size_t)(col0 + srow) * 1024 + scol;
    const short* bG1 = WT + (size_t)(col0 + srow + 64) * 1024 + scol;

    floatx4 acc[2][4] = {};

    {   // prologue: stage k-step 0
        *(short8*)(&Alds[0][srow][scol]) = *(const short8*)(aG);
        *(short8*)(&Blds[0][srow][scol]) = *(const short8*)(bG0);
        *(short8*)(&Blds[0][srow + 64][scol]) = *(const short8*)(bG1);
    }
    __syncthreads();

    const int nsteps = 1024 / 32;
    for (int it = 0; it < nsteps; ++it) {
        short8 ar, br0, br1;
        const bool more = (it + 1 < nsteps);
        if (more) {
            const int kk = (it + 1) * 32;
            ar  = *(const short8*)(aG + kk);
            br0 = *(const short8*)(bG0 + kk);
            br1 = *(const short8*)(bG1 + kk);
        }
        const int b = it & 1;
        short8 af[2], bf4[4];
#pragma unroll
        for (int i = 0; i < 2; ++i)
            af[i] = *(const short8*)(&Alds[b][wr * 32 + i * 16 + ln][quad * 8]);
#pragma unroll
        for (int t = 0; t < 4; ++t)
            bf4[t] = *(const short8*)(&Blds[b][wc * 64 + t * 16 + ln][quad * 8]);
#pragma unroll
        for (int i = 0; i < 2; ++i)
#pragma unroll
            for (int t = 0; t < 4; ++t)
                acc[i][t] = MFMA_BF16(af[i], bf4[t], acc[i][t]);
        if (more) {
            const int nb = (it + 1) & 1;
            *(short8*)(&Alds[nb][srow][scol]) = ar;
            *(short8*)(&Blds[nb][srow][scol]) = br0;
            *(short8*)(&Blds[nb][srow + 64][scol]) = br1;
        }
        __syncthreads();
    }

    const float oscale = (z == 0) ? QSCALE_LOG2E : 1.0f;
    short* dst = (z == 0) ? Qw : (z == 1) ? Kw : Vtw;
#pragma unroll
    for (int i = 0; i < 2; ++i)
#pragma unroll
        for (int t = 0; t < 4; ++t)
#pragma unroll
            for (int r = 0; r < 4; ++r) {
                const int R = row0 + wr * 32 + i * 16 + quad * 4 + r;
                const int C = col0 + wc * 64 + t * 16 + ln;
                const int b = R >> 11, n = R & 2047;
                const int h = C >> 6, d = C & 63;
                const short val = f2bf(acc[i][t][r] * oscale);
                if (z < 2)
                    dst[((b * 8 + h) * 2048 + n) * 64 + d] = val;
                else
                    dst[((b * 8 + h) * 64 + d) * 2048 + n] = val;
            }
}

// ---------- 3) flash attention: cooperative double-buffered LDS staging of K/V,
//              register-only P transform (S^T trick), no shuffles in loop ----------
__global__ __launch_bounds__(256, 3) void attn_kernel(const short* __restrict__ Q,
                                                      const short* __restrict__ K,
                                                      const short* __restrict__ Vt,
                                                      float* __restrict__ Opart,
                                                      float* __restrict__ lbuf,
                                                      int chunkLen) {
    const int tid = threadIdx.x;
    const int w = tid >> 6;
    const int lane = tid & 63;
    const int quad = lane >> 4;
    const int ln = lane & 15;
    const int q0 = blockIdx.x * 64;
    const int bh = blockIdx.y;  // b*8+h
    const int c = blockIdx.z;

    __shared__ __align__(16) short klds[2][64][72];
    __shared__ __align__(16) short vlds[2][64][72];

    const short* Qbh = Q + bh * 2048 * 64;
    const short* Kbh = K + bh * 2048 * 64;
    const short* Vbh = Vt + bh * 64 * 2048;

    short8 qf[2];
    {
        const int qrow = q0 + w * 16 + ln;
        qf[0] = *(const short8*)(Qbh + qrow * 64 + quad * 8);
        qf[1] = *(const short8*)(Qbh + qrow * 64 + 32 + quad * 8);
    }

    floatx4 ot[4] = {};   // O^T: lane holds d=dt*16+quad*4+r, qrow=ln
    float lp = 0.f;

    const int sr = tid >> 3;
    const int sc = (tid & 7) * 8;

    auto computeTile = [&](int b) {
        short8 kf[8];
#pragma unroll
        for (int t = 0; t < 4; ++t)
#pragma unroll
            for (int ks = 0; ks < 2; ++ks)
                kf[t * 2 + ks] = *(const short8*)(&klds[b][t * 16 + ln][ks * 32 + quad * 8]);
        bf16x4 vf[16];
#pragma unroll
        for (int dt = 0; dt < 4; ++dt)
#pragma unroll
            for (int t = 0; t < 4; ++t)
                vf[dt * 4 + t] = *(const bf16x4*)(&vlds[b][dt * 16 + ln][t * 16 + quad * 4]);

        floatx4 s[4] = {};
#pragma unroll
        for (int ks = 0; ks < 2; ++ks)
#pragma unroll
            for (int t = 0; t < 4; ++t)
                s[t] = MFMA_BF16(kf[t * 2 + ks], qf[ks], s[t]);

        bf16x4 pf[4];
#pragma unroll
        for (int t = 0; t < 4; ++t) {
            float p0 = fast_exp2(s[t][0]);
            float p1 = fast_exp2(s[t][1]);
            float p2 = fast_exp2(s[t][2]);
            float p3 = fast_exp2(s[t][3]);
            lp += (p0 + p1) + (p2 + p3);
            pf[t] = pack4(p0, p1, p2, p3);
        }
#pragma unroll
        for (int t = 0; t < 4; ++t)
#pragma unroll
            for (int dt = 0; dt < 4; ++dt)
                ot[dt] = mfma16(vf[dt * 4 + t], pf[t], ot[dt]);
    };

    const int j0s = c * chunkLen;
    const int nt = chunkLen >> 6;

    {
        short8 k0 = *(const short8*)(Kbh + j0s * 64 + tid * 8);
        short8 k1 = *(const short8*)(Kbh + j0s * 64 + (tid + 256) * 8);
        short8 v0 = *(const short8*)(Vbh + sr * 2048 + j0s + sc);
        short8 v1 = *(const short8*)(Vbh + (sr + 32) * 2048 + j0s + sc);
        *(short8*)(&klds[0][sr][sc]) = k0;
        *(short8*)(&klds[0][sr + 32][sc]) = k1;
        *(short8*)(&vlds[0][sr][sc]) = v0;
        *(short8*)(&vlds[0][sr + 32][sc]) = v1;
    }
    __syncthreads();

    for (int it = 0; it < nt; ++it) {
        short8 k0, k1, v0, v1;
        const bool more = (it + 1 < nt);
        if (more) {
            const int jn = j0s + (it + 1) * 64;
            k0 = *(const short8*)(Kbh + jn * 64 + tid * 8);
            k1 = *(const short8*)(Kbh + jn * 64 + (tid + 256) * 8);
            v0 = *(const short8*)(Vbh + sr * 2048 + jn + sc);
            v1 = *(const short8*)(Vbh + (sr + 32) * 2048 + jn + sc);
        }
        computeTile(it & 1);
        if (more) {
            const int nb = (it + 1) & 1;
            *(short8*)(&klds[nb][sr][sc]) = k0;
            *(short8*)(&klds[nb][sr + 32][sc]) = k1;
            *(short8*)(&vlds[nb][sr][sc]) = v0;
            *(short8*)(&vlds[nb][sr + 32][sc]) = v1;
        }
        __syncthreads();
    }

    lp += __shfl_xor(lp, 16);
    lp += __shfl_xor(lp, 32);

    const int n = q0 + w * 16 + ln;
    float* obase = Opart + (((size_t)(c * 16 + bh) * 2048 + n) * 64) + quad * 4;
#pragma unroll
    for (int dt = 0; dt < 4; ++dt)
        *(f32x4*)(obase + dt * 16) = ot[dt];
    if (quad == 0)
        lbuf[(size_t)(c * 16 + bh) * 2048 + n] = lp;
}

// ---------- 4) combine partials -> bf16 attn out [4096][512] ----------
__global__ __launch_bounds__(256) void combine_kernel(const float* __restrict__ Opart,
                                                      const float* __restrict__ lbuf,
                                                      short* __restrict__ Aw,
                                                      int nchunks) {
    const int d = threadIdx.x;
    const int rid = blockIdx.x * 4 + threadIdx.y;
    const int bh = rid >> 11, n = rid & 2047;

    float L = 0.f, O = 0.f;
    for (int c = 0; c < nchunks; ++c) {
        L += lbuf[(size_t)(c * 16 + bh) * 2048 + n];
        O += Opart[(((size_t)(c * 16 + bh) * 2048 + n) * 64) + d];
    }
    const int b = bh >> 3, h = bh & 7;
    Aw[((size_t)(b * 2048 + n) * 512) + h * 64 + d] = f2bf(O / L);
}

// ---------- 5) output GEMM + bias, LDS-staged double-buffer ----------
// out[4096][1024] = A[4096][512] @ Wo + bo; WoT [1024][512].
// Block 256 thr, BM=64 x BN=128, BK=32; wave tile 32x64.
__global__ __launch_bounds__(256, 4) void gemm_final(const short* __restrict__ A,
                                                     const short* __restrict__ WoT,
                                                     const float* __restrict__ bias,
                                                     float* __restrict__ out) {
    const int tid = threadIdx.x;
    const int w = tid >> 6;
    const int lane = tid & 63;
    const int quad = lane >> 4, ln = lane & 15;
    const int wr = w >> 1, wc = w & 1;
    const int row0 = blockIdx.x * 64;
    const int col0 = blockIdx.y * 128;

    __shared__ __align__(16) short Alds[2][64][32];
    __shared__ __align__(16) short Blds[2][128][32];

    const int srow = tid >> 2;
    const int scol = (tid & 3) * 8;
    const short* aG = A + (size_t)(row0 + srow) * 512 + scol;
    const short* bG0 = WoT + (size_t)(col0 + srow) * 512 + scol;
    const short* bG1 = WoT + (size_t)(col0 + srow + 64) * 512 + scol;

    floatx4 acc[2][4] = {};

    {
        *(short8*)(&Alds[0][srow][scol]) = *(const short8*)(aG);
        *(short8*)(&Blds[0][srow][scol]) = *(const short8*)(bG0);
        *(short8*)(&Blds[0][srow + 64][scol]) = *(const short8*)(bG1);
    }
    __syncthreads();

    const int nsteps = 512 / 32;
    for (int it = 0; it < nsteps; ++it) {
        short8 ar, br0, br1;
        const bool more = (it + 1 < nsteps);
        if (more) {
            const int kk = (it + 1) * 32;
            ar  = *(const short8*)(aG + kk);
            br0 = *(const short8*)(bG0 + kk);
            br1 = *(const short8*)(bG1 + kk);
        }
        const int b = it & 1;
        short8 af[2], bf4[4];
#pragma unroll
        for (int i = 0; i < 2; ++i)
            af[i] = *(const short8*)(&Alds[b][wr * 32 + i * 16 + ln][quad * 8]);
#pragma unroll
        for (int t = 0; t < 4; ++t)
            bf4[t] = *(const short8*)(&Blds[b][wc * 64 + t * 16 + ln][quad * 8]);
#pragma unroll
        for (int i = 0; i < 2; ++i)
#pragma unroll
            for (int t = 0; t < 4; ++t)
                acc[i][t] = MFMA_BF16(af[i], bf4[t], acc[i][t]);
        if (more) {
            const int nb = (it + 1) & 1;
            *(short8*)(&Alds[nb][srow][scol]) = ar;
            *(short8*)(&Blds[nb][srow][scol]) = br0;
            *(short8*)(&Blds[nb][srow + 64][scol]) = br1;
        }
        __syncthreads();
    }

#pragma unroll
    for (int i = 0; i < 2; ++i)
#pragma unroll
        for (int t = 0; t < 4; ++t)
#pragma unroll
            for (int r = 0; r < 4; ++r) {
                const int R = row0 + wr * 32 + i * 16 + quad * 4 + r;
                const int C = col0 + wc * 64 + t * 16 + ln;
                out[(size_t)R * 1024 + C] = acc[i][t][r] + bias[C];
            }
}

// ---------- launcher ----------
extern "C" void kernel_launch(void* const* d_in, const int* in_sizes, int n_in,
                              void* d_out, int out_size, void* d_ws, size_t ws_size,
                              hipStream_t stream) {
    const float* x   = (const float*)d_in[0];  // [2,2048,1024] f32
    const float* ctx = (const float*)d_in[1];
    const float* Wq  = (const float*)d_in[2];  // [1024,512]
    const float* Wk  = (const float*)d_in[3];
    const float* Wv  = (const float*)d_in[4];
    const float* Wo  = (const float*)d_in[5];  // [512,1024]
    const float* bo  = (const float*)d_in[6];  // [1024]
    float* out = (float*)d_out;                // [2,2048,1024] f32

    char* ws = (char*)d_ws;
    size_t off = 0;
    auto alloc = [&](size_t bytes) { char* p = ws + off; off += (bytes + 255) & ~(size_t)255; return p; };

    short* WqT  = (short*)alloc(512 * 1024 * 2);
    short* WkT  = (short*)alloc(512 * 1024 * 2);
    short* WvT  = (short*)alloc(512 * 1024 * 2);
    short* WoT  = (short*)alloc(1024 * 512 * 2);
    short* xb   = (short*)alloc((size_t)4096 * 1024 * 2);
    short* ctxb = (short*)alloc((size_t)4096 * 1024 * 2);
    short* Qw   = (short*)alloc((size_t)16 * 2048 * 64 * 2);
    short* Kw   = (short*)alloc((size_t)16 * 2048 * 64 * 2);
    short* Vtw  = (short*)alloc((size_t)16 * 2048 * 64 * 2);
    short* Aw   = (short*)alloc((size_t)4096 * 512 * 2);
    size_t base = off;
    const size_t perchunk = (size_t)16 * 2048 * 64 * 4 + (size_t)16 * 2048 * 4 + 512;
    int nchunks = 4;
    while (nchunks > 1 && base + (size_t)nchunks * perchunk > ws_size) nchunks >>= 1;
    float* Opart = (float*)alloc((size_t)nchunks * 16 * 2048 * 64 * 4);
    float* lbuf  = (float*)alloc((size_t)nchunks * 16 * 2048 * 4);
    const int chunkLen = 2048 / nchunks;

    cvt_f32_bf16<<<4096, 256, 0, stream>>>(x, ctx, xb, ctxb);
    transpose_all<<<dim3(32, 32, 4), dim3(32, 8), 0, stream>>>(Wq, Wk, Wv, Wo, WqT, WkT, WvT, WoT);

    gemm_qkv<<<dim3(64, 4, 3), 256, 0, stream>>>(xb, ctxb, WqT, WkT, WvT, Qw, Kw, Vtw);

    attn_kernel<<<dim3(32, 16, nchunks), 256, 0, stream>>>(Qw, Kw, Vtw, Opart, lbuf, chunkLen);
    combine_kernel<<<dim3(8192), dim3(64, 4), 0, stream>>>(Opart, lbuf, Aw, nchunks);

    gemm_final<<<dim3(64, 8), 256, 0, stream>>>(Aw, WoT, bo, out);
}

// Round 8
// 171.787 us; speedup vs baseline: 2.1091x; 1.0364x over previous
//
#include <hip/hip_runtime.h>

// ---------- types / helpers ----------
typedef __attribute__((ext_vector_type(8))) short short8;   // 8 bf16 = 4 VGPRs
typedef __attribute__((ext_vector_type(4))) short bf16x4;   // 4 bf16 = 2 VGPRs
typedef __attribute__((ext_vector_type(4))) float floatx4;  // MFMA C/D
typedef __attribute__((ext_vector_type(4))) float f32x4;

__device__ __forceinline__ short f2bf(float f) {
    union { float f; unsigned u; } v;
    v.f = f;
    unsigned r = v.u + 0x7fffu + ((v.u >> 16) & 1u);  // RNE
    return (short)(r >> 16);
}
__device__ __forceinline__ short8 cvt8(f32x4 a, f32x4 b) {
    short8 r;
    r[0] = f2bf(a[0]); r[1] = f2bf(a[1]); r[2] = f2bf(a[2]); r[3] = f2bf(a[3]);
    r[4] = f2bf(b[0]); r[5] = f2bf(b[1]); r[6] = f2bf(b[2]); r[7] = f2bf(b[3]);
    return r;
}
// round-half-up f32->bf16 pack of 4
__device__ __forceinline__ bf16x4 pack4(float a, float b, float c, float d) {
    union { float f; unsigned u; } x;
    unsigned ua, ub, uc, ud;
    x.f = a; ua = (x.u + 0x8000u) >> 16;
    x.f = b; ub = (x.u + 0x8000u) >> 16;
    x.f = c; uc = (x.u + 0x8000u) >> 16;
    x.f = d; ud = (x.u + 0x8000u) >> 16;
    union { bf16x4 s; unsigned u2[2]; } r;
    r.u2[0] = ua | (ub << 16);
    r.u2[1] = uc | (ud << 16);
    return r.s;
}

#define MFMA_BF16(a, b, c) __builtin_amdgcn_mfma_f32_16x16x32_bf16((a), (b), (c), 0, 0, 0)

__device__ __forceinline__ floatx4 mfma16(bf16x4 a, bf16x4 b, floatx4 c) {
#if __has_builtin(__builtin_amdgcn_mfma_f32_16x16x16bf16_1k)
    return __builtin_amdgcn_mfma_f32_16x16x16bf16_1k(a, b, c, 0, 0, 0);
#else
    floatx4 d;
    asm volatile("v_mfma_f32_16x16x16_bf16 %0, %1, %2, %3"
                 : "=&v"(d) : "v"(a), "v"(b), "v"(c));
    return d;
#endif
}

__device__ __forceinline__ float fast_exp2(float x) {
#if __has_builtin(__builtin_amdgcn_exp2f)
    return __builtin_amdgcn_exp2f(x);
#else
    return exp2f(x);
#endif
}

// scale(1/8) * log2(e): softmax in exp2 domain, folded into Q at proj time
#define QSCALE_LOG2E 0.18033688011112042f

// ---------- 1) all 4 weight transposes in one launch ----------
__global__ __launch_bounds__(256) void transpose_all(const float* __restrict__ Wq,
                                                     const float* __restrict__ Wk,
                                                     const float* __restrict__ Wv,
                                                     const float* __restrict__ Wo,
                                                     short* __restrict__ WqT,
                                                     short* __restrict__ WkT,
                                                     short* __restrict__ WvT,
                                                     short* __restrict__ WoT) {
    const int z = blockIdx.z;
    const float* src = (z == 0) ? Wq : (z == 1) ? Wk : (z == 2) ? Wv : Wo;
    short* dst = (z == 0) ? WqT : (z == 1) ? WkT : (z == 2) ? WvT : WoT;
    const int R = (z < 3) ? 1024 : 512;
    const int C = (z < 3) ? 512 : 1024;
    const int c0 = blockIdx.x * 32;
    const int r0 = blockIdx.y * 32;
    if (c0 >= C || r0 >= R) return;
    __shared__ float tile[32][33];
    const int tx = threadIdx.x;
    const int ty = threadIdx.y;
#pragma unroll
    for (int i = 0; i < 32; i += 8)
        tile[ty + i][tx] = src[(r0 + ty + i) * C + c0 + tx];
    __syncthreads();
#pragma unroll
    for (int i = 0; i < 32; i += 8)
        dst[(c0 + ty + i) * R + r0 + tx] = f2bf(tile[tx][ty + i]);
}

// ---------- 2) fused QKV projection GEMM, LDS-staged double-buffer ----------
// A is fp32 (x or ctx); converted to bf16 in the staging step (no cvt pass).
// Block 256 thr (4 waves), BM=64 x BN=128, BK=32; wave tile 32x64.
// z=0: Q (scaled), [bh][n][64]; z=1: K, [bh][n][64]; z=2: V^T, [bh][64][n].
__global__ __launch_bounds__(256, 4) void gemm_qkv(const float* __restrict__ x,
                                                   const float* __restrict__ ctx,
                                                   const short* __restrict__ WqT,
                                                   const short* __restrict__ WkT,
                                                   const short* __restrict__ WvT,
                                                   short* __restrict__ Qw,
                                                   short* __restrict__ Kw,
                                                   short* __restrict__ Vtw) {
    const int z = blockIdx.z;
    const float* A  = (z == 0) ? x : ctx;
    const short* WT = (z == 0) ? WqT : (z == 1) ? WkT : WvT;
    const int tid = threadIdx.x;
    const int w = tid >> 6;
    const int lane = tid & 63;
    const int quad = lane >> 4, ln = lane & 15;
    const int wr = w >> 1, wc = w & 1;
    const int row0 = blockIdx.x * 64;
    const int col0 = blockIdx.y * 128;

    __shared__ __align__(16) short Alds[2][64][32];
    __shared__ __align__(16) short Blds[2][128][32];

    const int srow = tid >> 2;          // 0..63
    const int scol = (tid & 3) * 8;     // 0,8,16,24
    const float* aG = A + (size_t)(row0 + srow) * 1024 + scol;
    const short* bG0 = WT + (size_t)(col0 + srow) * 1024 + scol;
    const short* bG1 = WT + (size_t)(col0 + srow + 64) * 1024 + scol;

    floatx4 acc[2][4] = {};

    {   // prologue: stage k-step 0 (A converted f32->bf16 in-register)
        f32x4 a0 = *(const f32x4*)(aG);
        f32x4 a1 = *(const f32x4*)(aG + 4);
        *(short8*)(&Alds[0][srow][scol]) = cvt8(a0, a1);
        *(short8*)(&Blds[0][srow][scol]) = *(const short8*)(bG0);
        *(short8*)(&Blds[0][srow + 64][scol]) = *(const short8*)(bG1);
    }
    __syncthreads();

    const int nsteps = 1024 / 32;
    for (int it = 0; it < nsteps; ++it) {
        f32x4 a0, a1;
        short8 br0, br1;
        const bool more = (it + 1 < nsteps);
        if (more) {
            const int kk = (it + 1) * 32;
            a0  = *(const f32x4*)(aG + kk);
            a1  = *(const f32x4*)(aG + kk + 4);
            br0 = *(const short8*)(bG0 + kk);
            br1 = *(const short8*)(bG1 + kk);
        }
        const int b = it & 1;
        short8 af[2], bf4[4];
#pragma unroll
        for (int i = 0; i < 2; ++i)
            af[i] = *(const short8*)(&Alds[b][wr * 32 + i * 16 + ln][quad * 8]);
#pragma unroll
        for (int t = 0; t < 4; ++t)
            bf4[t] = *(const short8*)(&Blds[b][wc * 64 + t * 16 + ln][quad * 8]);
#pragma unroll
        for (int i = 0; i < 2; ++i)
#pragma unroll
            for (int t = 0; t < 4; ++t)
                acc[i][t] = MFMA_BF16(af[i], bf4[t], acc[i][t]);
        if (more) {
            const int nb = (it + 1) & 1;
            *(short8*)(&Alds[nb][srow][scol]) = cvt8(a0, a1);
            *(short8*)(&Blds[nb][srow][scol]) = br0;
            *(short8*)(&Blds[nb][srow + 64][scol]) = br1;
        }
        __syncthreads();
    }

    const float oscale = (z == 0) ? QSCALE_LOG2E : 1.0f;
    short* dst = (z == 0) ? Qw : (z == 1) ? Kw : Vtw;
#pragma unroll
    for (int i = 0; i < 2; ++i)
#pragma unroll
        for (int t = 0; t < 4; ++t)
#pragma unroll
            for (int r = 0; r < 4; ++r) {
                const int R = row0 + wr * 32 + i * 16 + quad * 4 + r;
                const int C = col0 + wc * 64 + t * 16 + ln;
                const int b = R >> 11, n = R & 2047;
                const int h = C >> 6, d = C & 63;
                const short val = f2bf(acc[i][t][r] * oscale);
                if (z < 2)
                    dst[((b * 8 + h) * 2048 + n) * 64 + d] = val;
                else
                    dst[((b * 8 + h) * 64 + d) * 2048 + n] = val;
            }
}

// ---------- 3) flash attention, single pass over all 2048 keys ----------
// Cooperative double-buffered LDS staging of K/V; register-only P transform
// (S^T trick: C-layout of S^T == B-operand layout of 16x16x16 MFMA);
// no shuffles/barriers in math; normalizes and writes bf16 Aw directly.
__global__ __launch_bounds__(256, 2) void attn_kernel(const short* __restrict__ Q,
                                                      const short* __restrict__ K,
                                                      const short* __restrict__ Vt,
                                                      short* __restrict__ Aw) {
    const int tid = threadIdx.x;
    const int w = tid >> 6;
    const int lane = tid & 63;
    const int quad = lane >> 4;
    const int ln = lane & 15;
    const int q0 = blockIdx.x * 64;
    const int bh = blockIdx.y;  // b*8+h

    __shared__ __align__(16) short klds[2][64][72];
    __shared__ __align__(16) short vlds[2][64][72];

    const short* Qbh = Q + bh * 2048 * 64;
    const short* Kbh = K + bh * 2048 * 64;
    const short* Vbh = Vt + bh * 64 * 2048;

    short8 qf[2];
    {
        const int qrow = q0 + w * 16 + ln;
        qf[0] = *(const short8*)(Qbh + qrow * 64 + quad * 8);
        qf[1] = *(const short8*)(Qbh + qrow * 64 + 32 + quad * 8);
    }

    floatx4 ot[4] = {};   // O^T: lane holds d=dt*16+quad*4+r, qrow=ln
    float lp = 0.f;

    const int sr = tid >> 3;
    const int sc = (tid & 7) * 8;

    auto computeTile = [&](int b) {
        short8 kf[8];
#pragma unroll
        for (int t = 0; t < 4; ++t)
#pragma unroll
            for (int ks = 0; ks < 2; ++ks)
                kf[t * 2 + ks] = *(const short8*)(&klds[b][t * 16 + ln][ks * 32 + quad * 8]);
        bf16x4 vf[16];
#pragma unroll
        for (int dt = 0; dt < 4; ++dt)
#pragma unroll
            for (int t = 0; t < 4; ++t)
                vf[dt * 4 + t] = *(const bf16x4*)(&vlds[b][dt * 16 + ln][t * 16 + quad * 4]);

        floatx4 s[4] = {};
#pragma unroll
        for (int ks = 0; ks < 2; ++ks)
#pragma unroll
            for (int t = 0; t < 4; ++t)
                s[t] = MFMA_BF16(kf[t * 2 + ks], qf[ks], s[t]);

        bf16x4 pf[4];
#pragma unroll
        for (int t = 0; t < 4; ++t) {
            float p0 = fast_exp2(s[t][0]);
            float p1 = fast_exp2(s[t][1]);
            float p2 = fast_exp2(s[t][2]);
            float p3 = fast_exp2(s[t][3]);
            lp += (p0 + p1) + (p2 + p3);
            pf[t] = pack4(p0, p1, p2, p3);
        }
#pragma unroll
        for (int t = 0; t < 4; ++t)
#pragma unroll
            for (int dt = 0; dt < 4; ++dt)
                ot[dt] = mfma16(vf[dt * 4 + t], pf[t], ot[dt]);
    };

    const int nt = 2048 / 64;

    {   // prologue: stage tile 0
        short8 k0 = *(const short8*)(Kbh + tid * 8);
        short8 k1 = *(const short8*)(Kbh + (tid + 256) * 8);
        short8 v0 = *(const short8*)(Vbh + sr * 2048 + sc);
        short8 v1 = *(const short8*)(Vbh + (sr + 32) * 2048 + sc);
        *(short8*)(&klds[0][sr][sc]) = k0;
        *(short8*)(&klds[0][sr + 32][sc]) = k1;
        *(short8*)(&vlds[0][sr][sc]) = v0;
        *(short8*)(&vlds[0][sr + 32][sc]) = v1;
    }
    __syncthreads();

    for (int it = 0; it < nt; ++it) {
        short8 k0, k1, v0, v1;
        const bool more = (it + 1 < nt);
        if (more) {
            const int jn = (it + 1) * 64;
            k0 = *(const short8*)(Kbh + jn * 64 + tid * 8);
            k1 = *(const short8*)(Kbh + jn * 64 + (tid + 256) * 8);
            v0 = *(const short8*)(Vbh + sr * 2048 + jn + sc);
            v1 = *(const short8*)(Vbh + (sr + 32) * 2048 + jn + sc);
        }
        computeTile(it & 1);
        if (more) {
            const int nb = (it + 1) & 1;
            *(short8*)(&klds[nb][sr][sc]) = k0;
            *(short8*)(&klds[nb][sr + 32][sc]) = k1;
            *(short8*)(&vlds[nb][sr][sc]) = v0;
            *(short8*)(&vlds[nb][sr + 32][sc]) = v1;
        }
        __syncthreads();
    }

    // full row sum: keys split across quads
    lp += __shfl_xor(lp, 16);
    lp += __shfl_xor(lp, 32);
    const float invL = 1.0f / lp;

    // epilogue: normalize and write bf16 Aw[b*2048+n][h*64+d]
    const int n = q0 + w * 16 + ln;
    const int b = bh >> 3, h = bh & 7;
    short* abase = Aw + ((size_t)(b * 2048 + n) * 512) + h * 64 + quad * 4;
#pragma unroll
    for (int dt = 0; dt < 4; ++dt)
        *(bf16x4*)(abase + dt * 16) =
            pack4(ot[dt][0] * invL, ot[dt][1] * invL, ot[dt][2] * invL, ot[dt][3] * invL);
}

// ---------- 4) output GEMM + bias, LDS-staged double-buffer ----------
// out[4096][1024] = A[4096][512] @ Wo + bo; WoT [1024][512].
__global__ __launch_bounds__(256, 4) void gemm_final(const short* __restrict__ A,
                                                     const short* __restrict__ WoT,
                                                     const float* __restrict__ bias,
                                                     float* __restrict__ out) {
    const int tid = threadIdx.x;
    const int w = tid >> 6;
    const int lane = tid & 63;
    const int quad = lane >> 4, ln = lane & 15;
    const int wr = w >> 1, wc = w & 1;
    const int row0 = blockIdx.x * 64;
    const int col0 = blockIdx.y * 128;

    __shared__ __align__(16) short Alds[2][64][32];
    __shared__ __align__(16) short Blds[2][128][32];

    const int srow = tid >> 2;
    const int scol = (tid & 3) * 8;
    const short* aG = A + (size_t)(row0 + srow) * 512 + scol;
    const short* bG0 = WoT + (size_t)(col0 + srow) * 512 + scol;
    const short* bG1 = WoT + (size_t)(col0 + srow + 64) * 512 + scol;

    floatx4 acc[2][4] = {};

    {
        *(short8*)(&Alds[0][srow][scol]) = *(const short8*)(aG);
        *(short8*)(&Blds[0][srow][scol]) = *(const short8*)(bG0);
        *(short8*)(&Blds[0][srow + 64][scol]) = *(const short8*)(bG1);
    }
    __syncthreads();

    const int nsteps = 512 / 32;
    for (int it = 0; it < nsteps; ++it) {
        short8 ar, br0, br1;
        const bool more = (it + 1 < nsteps);
        if (more) {
            const int kk = (it + 1) * 32;
            ar  = *(const short8*)(aG + kk);
            br0 = *(const short8*)(bG0 + kk);
            br1 = *(const short8*)(bG1 + kk);
        }
        const int b = it & 1;
        short8 af[2], bf4[4];
#pragma unroll
        for (int i = 0; i < 2; ++i)
            af[i] = *(const short8*)(&Alds[b][wr * 32 + i * 16 + ln][quad * 8]);
#pragma unroll
        for (int t = 0; t < 4; ++t)
            bf4[t] = *(const short8*)(&Blds[b][wc * 64 + t * 16 + ln][quad * 8]);
#pragma unroll
        for (int i = 0; i < 2; ++i)
#pragma unroll
            for (int t = 0; t < 4; ++t)
                acc[i][t] = MFMA_BF16(af[i], bf4[t], acc[i][t]);
        if (more) {
            const int nb = (it + 1) & 1;
            *(short8*)(&Alds[nb][srow][scol]) = ar;
            *(short8*)(&Blds[nb][srow][scol]) = br0;
            *(short8*)(&Blds[nb][srow + 64][scol]) = br1;
        }
        __syncthreads();
    }

#pragma unroll
    for (int i = 0; i < 2; ++i)
#pragma unroll
        for (int t = 0; t < 4; ++t)
#pragma unroll
            for (int r = 0; r < 4; ++r) {
                const int R = row0 + wr * 32 + i * 16 + quad * 4 + r;
                const int C = col0 + wc * 64 + t * 16 + ln;
                out[(size_t)R * 1024 + C] = acc[i][t][r] + bias[C];
            }
}

// ---------- launcher ----------
extern "C" void kernel_launch(void* const* d_in, const int* in_sizes, int n_in,
                              void* d_out, int out_size, void* d_ws, size_t ws_size,
                              hipStream_t stream) {
    const float* x   = (const float*)d_in[0];  // [2,2048,1024] f32
    const float* ctx = (const float*)d_in[1];
    const float* Wq  = (const float*)d_in[2];  // [1024,512]
    const float* Wk  = (const float*)d_in[3];
    const float* Wv  = (const float*)d_in[4];
    const float* Wo  = (const float*)d_in[5];  // [512,1024]
    const float* bo  = (const float*)d_in[6];  // [1024]
    float* out = (float*)d_out;                // [2,2048,1024] f32

    char* ws = (char*)d_ws;
    size_t off = 0;
    auto alloc = [&](size_t bytes) { char* p = ws + off; off += (bytes + 255) & ~(size_t)255; return p; };

    short* WqT  = (short*)alloc(512 * 1024 * 2);     // [512][1024] bf16
    short* WkT  = (short*)alloc(512 * 1024 * 2);
    short* WvT  = (short*)alloc(512 * 1024 * 2);
    short* WoT  = (short*)alloc(1024 * 512 * 2);     // [1024][512] bf16
    short* Qw   = (short*)alloc((size_t)16 * 2048 * 64 * 2);
    short* Kw   = (short*)alloc((size_t)16 * 2048 * 64 * 2);
    short* Vtw  = (short*)alloc((size_t)16 * 2048 * 64 * 2);
    short* Aw   = (short*)alloc((size_t)4096 * 512 * 2);

    transpose_all<<<dim3(32, 32, 4), dim3(32, 8), 0, stream>>>(Wq, Wk, Wv, Wo, WqT, WkT, WvT, WoT);

    gemm_qkv<<<dim3(64, 4, 3), 256, 0, stream>>>(x, ctx, WqT, WkT, WvT, Qw, Kw, Vtw);

    attn_kernel<<<dim3(32, 16), 256, 0, stream>>>(Qw, Kw, Vtw, Aw);

    gemm_final<<<dim3(64, 8), 256, 0, stream>>>(Aw, WoT, bo, out);
}